// Round 1
// baseline (2650.460 us; speedup 1.0000x reference)
//
#include <hip/hip_runtime.h>
#include <hip/hip_bf16.h>
#include <cstdint>

// Problem constants
constexpr int kB = 512;      // batch
constexpr int kT = 80;       // encoder seq len
constexpr int kC = 512;      // in_channels
constexpr int kH = 256;      // hidden
constexpr int kV = 6625;     // classes
constexpr int kGIN = kC + kV; // 7137, gru_wih leading dim

typedef __attribute__((ext_vector_type(8))) short short8;
typedef __attribute__((ext_vector_type(4))) float floatx4;

__device__ __forceinline__ float fast_tanh(float x) {
  float e = __expf(2.f * x);
  return 1.f - 2.f / (e + 1.f);
}
__device__ __forceinline__ float fast_sig(float x) {
  return 1.f / (1.f + __expf(-x));
}

__device__ __forceinline__ void gld_lds16(const void* g, void* l) {
  __builtin_amdgcn_global_load_lds(
      (const __attribute__((address_space(1))) void*)(uintptr_t)g,
      (__attribute__((address_space(3))) void*)(uintptr_t)l, 16, 0, 0);
}

// ---------------------------------------------------------------------------
// fp32 -> bf16 conversion (gen_w)
// ---------------------------------------------------------------------------
__global__ __launch_bounds__(256) void cvt_bf16(const float* __restrict__ x,
                                                __hip_bfloat16* __restrict__ y,
                                                int n) {
  int i = blockIdx.x * 256 + threadIdx.x;
  if (i < n) y[i] = __float2bfloat16(x[i]);
}

// ---------------------------------------------------------------------------
// fp32 tiled GEMM: C[M,N] = A[M,K] * W[N,K]^T (+ epilogue per MODE)
// MODE 0: plain, no bias (proj).
// MODE 1: dual weight: n<kH -> (W0,b0)=h2h, else (W1,b1)=gru_whh. (ph|gh)
// MODE 2: W0=gru_wih (ldw=7137, scalar loads), +b0[n] + W0[n,512+tgt[m]] (gi)
// 64x64 tile, BK=16, 256 threads, 4x4 microtile. All dims divide evenly.
// ---------------------------------------------------------------------------
template <int MODE>
__global__ __launch_bounds__(256) void gemm64(
    const float* __restrict__ A, int lda,
    const float* __restrict__ W0, const float* __restrict__ bias0,
    const float* __restrict__ W1, const float* __restrict__ bias1,
    int ldw, float* __restrict__ C, int ldc,
    int M, int N, int K,
    const int* __restrict__ tgt, int s, int S) {
  __shared__ __align__(16) float As[16][72];
  __shared__ __align__(16) float Ws[16][72];
  const int tid = threadIdx.x;
  const int m0 = blockIdx.x * 64;
  const int n0 = blockIdx.y * 64;
  const float* W = W0;
  const float* bias = bias0;
  int nb = n0;
  if (MODE == 1 && n0 >= kH) { W = W1; bias = bias1; nb = n0 - kH; }
  const int lrow = tid >> 2, lkq = tid & 3;
  const int ty = tid >> 4, tx = tid & 15;
  float acc[4][4] = {};
  for (int k0 = 0; k0 < K; k0 += 16) {
    const float* ap = A + (size_t)(m0 + lrow) * lda + k0 + lkq * 4;
    float4 av = *(const float4*)ap;
    const float* wp = W + (size_t)(nb + lrow) * ldw + k0 + lkq * 4;
    float4 wv;
    if (MODE == 2) { wv.x = wp[0]; wv.y = wp[1]; wv.z = wp[2]; wv.w = wp[3]; }
    else wv = *(const float4*)wp;
    As[lkq * 4 + 0][lrow] = av.x;
    As[lkq * 4 + 1][lrow] = av.y;
    As[lkq * 4 + 2][lrow] = av.z;
    As[lkq * 4 + 3][lrow] = av.w;
    Ws[lkq * 4 + 0][lrow] = wv.x;
    Ws[lkq * 4 + 1][lrow] = wv.y;
    Ws[lkq * 4 + 2][lrow] = wv.z;
    Ws[lkq * 4 + 3][lrow] = wv.w;
    __syncthreads();
#pragma unroll
    for (int k = 0; k < 16; ++k) {
      float4 a = *(const float4*)&As[k][ty * 4];
      float4 w = *(const float4*)&Ws[k][tx * 4];
      acc[0][0] += a.x * w.x; acc[0][1] += a.x * w.y; acc[0][2] += a.x * w.z; acc[0][3] += a.x * w.w;
      acc[1][0] += a.y * w.x; acc[1][1] += a.y * w.y; acc[1][2] += a.y * w.z; acc[1][3] += a.y * w.w;
      acc[2][0] += a.z * w.x; acc[2][1] += a.z * w.y; acc[2][2] += a.z * w.z; acc[2][3] += a.z * w.w;
      acc[3][0] += a.w * w.x; acc[3][1] += a.w * w.y; acc[3][2] += a.w * w.z; acc[3][3] += a.w * w.w;
    }
    __syncthreads();
  }
#pragma unroll
  for (int i = 0; i < 4; ++i) {
#pragma unroll
    for (int j = 0; j < 4; ++j) {
      int m = m0 + ty * 4 + i;
      int n = n0 + tx * 4 + j;
      float v = acc[i][j];
      if (MODE == 1) v += bias[nb + tx * 4 + j];
      if (MODE == 2) v += bias0[n] + W0[(size_t)n * ldw + kC + tgt[m * S + s]];
      C[(size_t)m * ldc + n] = v;
    }
  }
}

// ---------------------------------------------------------------------------
// Attention: per block b: e[t]=sum_h tanh(proj[b,t,h]+ph[b,h])*score_w[h],
// softmax over T, context[b,c]=sum_t alpha_t*inputs[b,t,c]
// ---------------------------------------------------------------------------
__global__ __launch_bounds__(256) void attn_kernel(
    const float* __restrict__ phgh, const float* __restrict__ proj,
    const float* __restrict__ score_w, const float* __restrict__ inputs,
    float* __restrict__ ctx) {
  __shared__ __align__(16) float ph_s[kH];
  __shared__ __align__(16) float sw_s[kH];
  __shared__ float e_s[kT];
  const int b = blockIdx.x;
  const int tid = threadIdx.x;
  ph_s[tid] = phgh[b * 1024 + tid];
  sw_s[tid] = score_w[tid];
  __syncthreads();
  const int wave = tid >> 6, lane = tid & 63;
  float4 p4 = ((const float4*)ph_s)[lane];
  float4 s4 = ((const float4*)sw_s)[lane];
  for (int t = wave; t < kT; t += 4) {
    const float* pp = proj + (size_t)(b * kT + t) * kH + lane * 4;
    float4 r = *(const float4*)pp;
    float part = fast_tanh(r.x + p4.x) * s4.x + fast_tanh(r.y + p4.y) * s4.y +
                 fast_tanh(r.z + p4.z) * s4.z + fast_tanh(r.w + p4.w) * s4.w;
#pragma unroll
    for (int off = 32; off > 0; off >>= 1) part += __shfl_xor(part, off);
    if (lane == 0) e_s[t] = part;
  }
  __syncthreads();
  if (wave == 0) {
    float v0 = e_s[lane];
    float v1 = (lane < kT - 64) ? e_s[64 + lane] : -1e30f;
    float mx = fmaxf(v0, v1);
#pragma unroll
    for (int off = 32; off > 0; off >>= 1) mx = fmaxf(mx, __shfl_xor(mx, off));
    float x0 = __expf(v0 - mx);
    float x1 = (lane < kT - 64) ? __expf(v1 - mx) : 0.f;
    float sm = x0 + x1;
#pragma unroll
    for (int off = 32; off > 0; off >>= 1) sm += __shfl_xor(sm, off);
    float inv = 1.f / sm;
    e_s[lane] = x0 * inv;
    if (lane < kT - 64) e_s[64 + lane] = x1 * inv;
  }
  __syncthreads();
  float c0 = 0.f, c1 = 0.f;
  const float* ib = inputs + (size_t)b * kT * kC;
  for (int t = 0; t < kT; ++t) {
    float a = e_s[t];
    c0 += a * ib[t * kC + tid];
    c1 += a * ib[t * kC + 256 + tid];
  }
  ctx[b * kC + tid] = c0;
  ctx[b * kC + 256 + tid] = c1;
}

// ---------------------------------------------------------------------------
// GRU cell update (PyTorch GRUCell semantics)
// ---------------------------------------------------------------------------
__global__ __launch_bounds__(256) void gru_update(
    const float* __restrict__ gi, const float* __restrict__ phgh,
    const float* __restrict__ hp, float* __restrict__ hn,
    __hip_bfloat16* __restrict__ hidd, int s, int S) {
  const int b = blockIdx.x, h = threadIdx.x;
  float i_r = gi[b * 768 + h];
  float i_z = gi[b * 768 + 256 + h];
  float i_n = gi[b * 768 + 512 + h];
  float h_r = phgh[b * 1024 + 256 + h];
  float h_z = phgh[b * 1024 + 512 + h];
  float h_n = phgh[b * 1024 + 768 + h];
  float hv = hp[b * 256 + h];
  float r = fast_sig(i_r + h_r);
  float z = fast_sig(i_z + h_z);
  float n = fast_tanh(i_n + r * h_n);
  float o = (1.f - z) * n + z * hv;
  hn[b * 256 + h] = o;
  hidd[(size_t)(b * S + s) * kH + h] = __float2bfloat16(o);
}

// ---------------------------------------------------------------------------
// Final GEMM, bf16 MFMA: C[M,N] = A[M,K] * W[N,K]^T + bias[n]
// 128x128 tile, BK=32, 4 waves in 2x2, 16x16x32 mfma, global_load_lds x16.
// M=12800 (divides 128), N=6625 (guarded), K=256.
// ---------------------------------------------------------------------------
__global__ __launch_bounds__(256) void final_gemm(
    const __hip_bfloat16* __restrict__ A, const __hip_bfloat16* __restrict__ W,
    const float* __restrict__ bias, float* __restrict__ C, int M, int N, int K) {
  __shared__ __align__(16) short As[128 * 32];
  __shared__ __align__(16) short Ws[128 * 32];
  const int tid = threadIdx.x;
  const int wave = tid >> 6, lane = tid & 63;
  const int m0 = blockIdx.x * 128, n0 = blockIdx.y * 128;
  floatx4 acc[4][4] = {};
  const int lr = lane & 15;
  const int lkb = (lane >> 4) * 8;           // frag k offset (elements)
  const int mloc = (wave & 1) * 64;
  const int nloc = (wave >> 1) * 64;
  const int srow = wave * 16 + (lane >> 2);  // staging row within a 64-row round
  const int skq = (lane & 3) * 8;            // staging k offset (elements)
  for (int kt = 0; kt < K; kt += 32) {
#pragma unroll
    for (int r = 0; r < 2; ++r) {
      int rowA = r * 64 + srow;
      const __hip_bfloat16* ga = A + (size_t)(m0 + rowA) * K + kt + skq;
      gld_lds16(ga, (char*)As + (size_t)(r * 64 + wave * 16) * 64);
      int rowW = n0 + rowA;
      if (rowW > N - 1) rowW = N - 1;  // clamp; stores are guarded
      const __hip_bfloat16* gw = W + (size_t)rowW * K + kt + skq;
      gld_lds16(gw, (char*)Ws + (size_t)(r * 64 + wave * 16) * 64);
    }
    __syncthreads();
    short8 af[4], wf[4];
#pragma unroll
    for (int i = 0; i < 4; ++i)
      af[i] = *(const short8*)(As + (mloc + i * 16 + lr) * 32 + lkb);
#pragma unroll
    for (int j = 0; j < 4; ++j)
      wf[j] = *(const short8*)(Ws + (nloc + j * 16 + lr) * 32 + lkb);
#pragma unroll
    for (int i = 0; i < 4; ++i)
#pragma unroll
      for (int j = 0; j < 4; ++j)
        acc[i][j] = __builtin_amdgcn_mfma_f32_16x16x32_bf16(af[i], wf[j], acc[i][j], 0, 0, 0);
    __syncthreads();
  }
#pragma unroll
  for (int i = 0; i < 4; ++i) {
#pragma unroll
    for (int j = 0; j < 4; ++j) {
      int col = n0 + nloc + j * 16 + lr;
      if (col < N) {
        int rowb = m0 + mloc + i * 16 + ((lane >> 4) << 2);
        float bs = bias[col];
#pragma unroll
        for (int r = 0; r < 4; ++r)
          C[(size_t)(rowb + r) * N + col] = acc[i][j][r] + bs;
      }
    }
  }
}

// ---------------------------------------------------------------------------
extern "C" void kernel_launch(void* const* d_in, const int* in_sizes, int n_in,
                              void* d_out, int out_size, void* d_ws, size_t ws_size,
                              hipStream_t stream) {
  const float* inputs  = (const float*)d_in[0];
  const int*   targets = (const int*)d_in[1];
  // d_in[2] = batch_max_length (device scalar); S derived from out_size instead
  const float* i2h_w   = (const float*)d_in[3];
  const float* h2h_w   = (const float*)d_in[4];
  const float* h2h_b   = (const float*)d_in[5];
  const float* score_w = (const float*)d_in[6];
  const float* gru_wih = (const float*)d_in[7];
  const float* gru_whh = (const float*)d_in[8];
  const float* gru_bih = (const float*)d_in[9];
  const float* gru_bhh = (const float*)d_in[10];
  const float* gen_w   = (const float*)d_in[11];
  const float* gen_b   = (const float*)d_in[12];
  float* out = (float*)d_out;
  const int S = out_size / (kB * kV);  // 25

  // workspace carve (~58 MB total)
  char* ws = (char*)d_ws;
  size_t off = 0;
  auto alloc = [&](size_t bytes) {
    void* p = ws + off;
    off += (bytes + 255) & ~(size_t)255;
    return p;
  };
  float* proj  = (float*)alloc((size_t)kB * kT * kH * 4);   // 41.9 MB
  float* phgh  = (float*)alloc((size_t)kB * 4 * kH * 4);    // 2 MB   [ph|gh]
  float* ctx   = (float*)alloc((size_t)kB * kC * 4);        // 1 MB
  float* gi    = (float*)alloc((size_t)kB * 3 * kH * 4);    // 1.5 MB
  float* h0buf = (float*)alloc((size_t)kB * kH * 4);
  float* h1buf = (float*)alloc((size_t)kB * kH * 4);
  __hip_bfloat16* hidd = (__hip_bfloat16*)alloc((size_t)kB * S * kH * 2);
  __hip_bfloat16* gw16 = (__hip_bfloat16*)alloc((size_t)kV * kH * 2);

  hipMemsetAsync(h0buf, 0, (size_t)kB * kH * 4, stream);  // hidden0 = 0

  cvt_bf16<<<dim3((kV * kH + 255) / 256), 256, 0, stream>>>(gen_w, gw16, kV * kH);

  // proj = inputs @ i2h_w^T   [B*T, H], K=C
  gemm64<0><<<dim3(kB * kT / 64, kH / 64), 256, 0, stream>>>(
      inputs, kC, i2h_w, nullptr, nullptr, nullptr, kC,
      proj, kH, kB * kT, kH, kC, nullptr, 0, 0);

  for (int s = 0; s < S; ++s) {
    float* hp = (s & 1) ? h1buf : h0buf;
    float* hn = (s & 1) ? h0buf : h1buf;
    // phgh = h @ [h2h_w; gru_whh]^T + [h2h_b; gru_bhh]   [B, 4H], K=H
    gemm64<1><<<dim3(kB / 64, 1024 / 64), 256, 0, stream>>>(
        hp, kH, h2h_w, h2h_b, gru_whh, gru_bhh, kH,
        phgh, 1024, kB, 1024, kH, nullptr, 0, 0);
    attn_kernel<<<dim3(kB), 256, 0, stream>>>(phgh, proj, score_w, inputs, ctx);
    // gi = ctx @ wih[:, :C]^T + bih + wih[:, C+tgt]   [B, 3H], K=C
    gemm64<2><<<dim3(kB / 64, 768 / 64), 256, 0, stream>>>(
        ctx, kC, gru_wih, gru_bih, nullptr, nullptr, kGIN,
        gi, 768, kB, 768, kC, targets, s, S);
    gru_update<<<dim3(kB), 256, 0, stream>>>(gi, phgh, hp, hn, hidd, s, S);
  }

  // probs = hidd @ gen_w^T + gen_b   [B*S, V], K=H (bf16 MFMA)
  final_gemm<<<dim3(kB * S / 128, (kV + 127) / 128), 256, 0, stream>>>(
      hidd, gw16, gen_b, out, kB * S, kV, kH);
}